// Round 3
// baseline (329.774 us; speedup 1.0000x reference)
//
#include <hip/hip_runtime.h>
#include <hip/hip_bf16.h>

#define BATCH   32768
#define DIM     2048
#define NHEADS  28
#define NCOLS   280
#define LOSS_SCALE (1.0f / (float)(BATCH * NHEADS))

typedef __attribute__((ext_vector_type(8))) short short8;
typedef __attribute__((ext_vector_type(4))) float f32x4;

__device__ __forceinline__ short f2bf(float f) {
    union { __hip_bfloat16 h; short s; } u; u.h = __float2bfloat16(f); return u.s;
}

// ---------------------------------------------------------------------------
// W pre-swizzle: W [280][2048] f32 -> Wswz bf16 in MFMA B-fragment order.
//   short index = ((nhn*64 + kt64)*512) + lane*8 + j   (frag-major granules)
//   n = nhn-col-subtile*16 + (lane&15), d = kt64*32 + (lane>>4)*8 + j
// ---------------------------------------------------------------------------
__global__ void mvh_swz(const float* __restrict__ W, short* __restrict__ Wswz) {
    int t = blockIdx.x * 256 + threadIdx.x;      // 73728 threads
    int lane = t & 63;
    int ks = (t >> 6) & 63;
    int nt = t >> 12;                            // 0..17
    int n = nt * 16 + (lane & 15);
    int d = ks * 32 + (lane >> 4) * 8;
    short8 v;
    #pragma unroll
    for (int j = 0; j < 8; j++) v[j] = 0;
    if (n < NCOLS) {
        const float* src = W + (size_t)n * DIM + d;
        #pragma unroll
        for (int j = 0; j < 8; j++) v[j] = f2bf(src[j]);
    }
    *(short8*)(Wswz + (size_t)t * 8) = v;
}

// ---------------------------------------------------------------------------
// GEMM: logits[b][n] = sum_d hidden[b][d]*W[n][d] + bias[n]
// 256 blocks x 512 threads. BM=128, BK=64, 32 K-tiles.
// Waves: kph = w>>2 (K-phase split, even/odd tiles), wsub=(w>>1)&1 (64 rows),
// nhalf=w&1 (144 cols). acc = 4m x 9n f32x4.
// A: reg-staged fp32 -> bf16 frag-major LDS (padded frags). B: global_load_lds
// DMA from frag-ordered Wswz (L2-resident). Counted vmcnt, raw barriers.
// ---------------------------------------------------------------------------
#define AFRAG_PITCH 1040
#define A_BUF_BYTES (16 * AFRAG_PITCH)          // 16640
#define B_BUF_BYTES 36864

#define WAITVM(N) asm volatile("s_waitcnt vmcnt(" #N ")" ::: "memory")
#define SB0() __builtin_amdgcn_sched_barrier(0)
#define BAR() do { SB0(); __builtin_amdgcn_s_barrier(); SB0(); } while (0)

__global__ __launch_bounds__(512, 2)
void mvh_gemm(const float* __restrict__ hidden, const short* __restrict__ Wswz,
              const float* __restrict__ bias, float* __restrict__ logits) {
    __shared__ __align__(16) char lds[2 * A_BUF_BYTES + 2 * B_BUF_BYTES]; // 107008
    char* Ab0 = lds;
    char* Ab1 = lds + A_BUF_BYTES;
    char* Bb0 = lds + 2 * A_BUF_BYTES;
    char* Bb1 = lds + 2 * A_BUF_BYTES + B_BUF_BYTES;

    const int tid  = threadIdx.x;
    const int lane = tid & 63;
    const int wave = tid >> 6;          // 0..7
    const int kph  = wave >> 2;         // 0/1: even/odd K-tiles
    const int wsub = (wave >> 1) & 1;   // 64-row slice
    const int nhalf = wave & 1;         // 144-col half
    const int l15 = lane & 15, lhi = lane >> 4;
    const int rowbase = blockIdx.x * 128;

    // --- A staging mapping: thread stages 16 floats of row srow ---
    const int srow = tid >> 2;                  // 0..127
    const int skf  = (tid & 3) * 16;            // k-float offset
    const float* gA = hidden + (size_t)(rowbase + srow) * DIM + skf;
    const int sfrag = (srow >> 4) * 2 + (skf >> 5);
    const int slhi  = (skf & 31) >> 3;          // 0 or 2
    const int awb   = sfrag * AFRAG_PITCH + ((srow & 15) + 16 * slhi) * 16;

    f32x4 acc[4][9];
    #pragma unroll
    for (int m = 0; m < 4; m++)
        #pragma unroll
        for (int n = 0; n < 9; n++)
            acc[m][n] = (f32x4)0.0f;

    f32x4 a00, a01, a02, a03;   // slot 0 (even prefetch)
    f32x4 a10, a11, a12, a13;   // slot 1 (odd prefetch)

#define STAGE_B(dstbase, kt) do { \
    _Pragma("unroll") \
    for (int i_ = 0; i_ < 5; i_++) { \
        int g_ = (i_ < 4) ? (i_ * 512 + tid) : (2048 + (tid & 255)); \
        int f_ = g_ >> 6; \
        const short* gp_ = Wswz + (size_t)((f_ >> 1) * 64 + (kt) * 2 + (f_ & 1)) * 512 + (g_ & 63) * 8; \
        char* lp_ = (dstbase) + g_ * 16; \
        __builtin_amdgcn_global_load_lds((const __attribute__((address_space(1))) void*)gp_, \
            (__attribute__((address_space(3))) void*)lp_, 16, 0, 0); \
    } \
    SB0(); \
} while (0)

#define LOAD_A(r0, r1, r2, r3, kt) do { \
    const float* p_ = gA + (kt) * 64; \
    r0 = *(const f32x4*)(p_);      r1 = *(const f32x4*)(p_ + 4); \
    r2 = *(const f32x4*)(p_ + 8);  r3 = *(const f32x4*)(p_ + 12); \
    SB0(); \
} while (0)

#define WRITE_A(dstbase, r0, r1, r2, r3) do { \
    short8 s1_, s2_; \
    _Pragma("unroll") \
    for (int j_ = 0; j_ < 4; j_++) { \
        s1_[j_] = f2bf(r0[j_]); s1_[4 + j_] = f2bf(r1[j_]); \
        s2_[j_] = f2bf(r2[j_]); s2_[4 + j_] = f2bf(r3[j_]); \
    } \
    *(short8*)((dstbase) + awb)       = s1_; \
    *(short8*)((dstbase) + awb + 256) = s2_; \
} while (0)

#define COMPUTE(Abase, Bbase) do { \
    _Pragma("unroll") \
    for (int ks_ = 0; ks_ < 2; ks_++) { \
        short8 af_[4]; \
        _Pragma("unroll") \
        for (int m_ = 0; m_ < 4; m_++) \
            af_[m_] = *(const short8*)((Abase) + ((wsub * 4 + m_) * 2 + ks_) * AFRAG_PITCH + lane * 16); \
        _Pragma("unroll") \
        for (int n_ = 0; n_ < 9; n_++) { \
            short8 bf_ = *(const short8*)((Bbase) + ((nhalf * 9 + n_) * 2 + ks_) * 1024 + lane * 16); \
            _Pragma("unroll") \
            for (int m_ = 0; m_ < 4; m_++) \
                acc[m_][n_] = __builtin_amdgcn_mfma_f32_16x16x32_bf16(af_[m_], bf_, acc[m_][n_], 0, 0, 0); \
        } \
    } \
} while (0)

    // ---- prologue: A(0) -> Ab0, B(0) -> Bb0, A(1) -> slot1 regs ----
    LOAD_A(a00, a01, a02, a03, 0);
    WAITVM(0);
    WRITE_A(Ab0, a00, a01, a02, a03);
    STAGE_B(Bb0, 0);                 // 5 issues
    LOAD_A(a10, a11, a12, a13, 1);   // 4 issues
    WAITVM(4);                       // drain B(0), keep A(1) flying
    BAR();

    // ---- main loop: tiles 0..29 (double iterations) ----
    #pragma unroll 1
    for (int tp = 0; tp < 15; tp++) {
        const int e = tp * 2;
        // tile e (even, buffers 0). queue: [A(e+1):4]
        STAGE_B(Bb1, e + 1);                 // +5
        LOAD_A(a00, a01, a02, a03, e + 2);   // +4  -> 13
        if (kph == 0) COMPUTE(Ab0, Bb0);
        WAITVM(9);                           // A(e+1) done
        WRITE_A(Ab1, a10, a11, a12, a13);
        WAITVM(4);                           // B(e+1) done, A(e+2) flying
        BAR();
        // tile e+1 (odd, buffers 1). queue: [A(e+2):4]
        STAGE_B(Bb0, e + 2);                 // +5
        LOAD_A(a10, a11, a12, a13, e + 3);   // +4  -> 13
        if (kph == 1) COMPUTE(Ab1, Bb1);
        WAITVM(9);                           // A(e+2) done
        WRITE_A(Ab0, a00, a01, a02, a03);
        WAITVM(4);                           // B(e+2) done, A(e+3) flying
        BAR();
    }

    // ---- tail: tiles 30, 31. queue: [A(31):4] ----
    STAGE_B(Bb1, 31);                        // +5 -> 9
    if (kph == 0) COMPUTE(Ab0, Bb0);         // tile 30
    WAITVM(5);                               // A(31) done
    WRITE_A(Ab1, a10, a11, a12, a13);
    WAITVM(0);                               // B(31) done
    BAR();
    if (kph == 1) COMPUTE(Ab1, Bb1);         // tile 31

    // ---- epilogue: cross-kphase reduction + store ----
    #pragma unroll 1
    for (int m = 0; m < 4; m++) {
        __syncthreads();
        if (kph == 1) {
            char* dst = lds + (wave & 3) * 9216;
            #pragma unroll
            for (int n = 0; n < 9; n++)
                *(f32x4*)(dst + (n * 64 + lane) * 16) = acc[m][n];
        }
        __syncthreads();
        if (kph == 0) {
            const char* src = lds + wave * 9216;
            #pragma unroll
            for (int n = 0; n < 9; n++) {
                f32x4 p = *(const f32x4*)(src + (n * 64 + lane) * 16);
                int c = nhalf * 144 + n * 16 + l15;
                if (c < NCOLS) {
                    float bv = bias[c];
                    int row0 = rowbase + wsub * 64 + m * 16 + lhi * 4;
                    #pragma unroll
                    for (int r = 0; r < 4; r++)
                        logits[(size_t)(row0 + r) * NCOLS + c] = acc[m][n][r] + p[r] + bv;
                }
            }
        }
    }
#undef STAGE_B
#undef LOAD_A
#undef WRITE_A
#undef COMPUTE
}

// ---------------------------------------------------------------------------
// Loss: one thread per (row, head). nll = logsumexp(10) - x[label].
// ---------------------------------------------------------------------------
__global__ __launch_bounds__(256)
void mvh_loss(const float* __restrict__ logits, const int* __restrict__ labels,
              float* __restrict__ loss_out) {
    int gid = blockIdx.x * 256 + threadIdx.x;    // 917504 = 3584*256 exactly
    const float* p = logits + (size_t)gid * 10;
    float x[10];
    #pragma unroll
    for (int j = 0; j < 10; j++) x[j] = p[j];
    float m = x[0];
    #pragma unroll
    for (int j = 1; j < 10; j++) m = fmaxf(m, x[j]);
    float s = 0.0f;
    #pragma unroll
    for (int j = 0; j < 10; j++) s += __expf(x[j] - m);
    int lab = labels[gid];
    float xl = x[0];
    #pragma unroll
    for (int j = 1; j < 10; j++) xl = (lab == j) ? x[j] : xl;
    float nll = m + __logf(s) - xl;

    #pragma unroll
    for (int off = 32; off > 0; off >>= 1)
        nll += __shfl_down(nll, off, 64);

    __shared__ float part[4];
    int lane = threadIdx.x & 63, wv = threadIdx.x >> 6;
    if (lane == 0) part[wv] = nll;
    __syncthreads();
    if (threadIdx.x == 0)
        atomicAdd(loss_out, (part[0] + part[1] + part[2] + part[3]) * LOSS_SCALE);
}

extern "C" void kernel_launch(void* const* d_in, const int* in_sizes, int n_in,
                              void* d_out, int out_size, void* d_ws, size_t ws_size,
                              hipStream_t stream) {
    const float* hidden = (const float*)d_in[0];
    const int* labels   = (const int*)d_in[1];
    const float* W      = (const float*)d_in[2];
    const float* bias   = (const float*)d_in[3];
    float* out = (float*)d_out;
    short* Wswz = (short*)d_ws;   // 589824 bf16 = 1.18 MB

    hipMemsetAsync(d_out, 0, sizeof(float), stream);           // zero loss accumulator
    mvh_swz<<<288, 256, 0, stream>>>(W, Wswz);
    mvh_gemm<<<256, 512, 0, stream>>>(hidden, Wswz, bias, out + 1);
    mvh_loss<<<3584, 256, 0, stream>>>(out + 1, labels, out);
}

// Round 4
// 141.730 us; speedup vs baseline: 2.3268x; 2.3268x over previous
//
#include <hip/hip_runtime.h>
#include <hip/hip_bf16.h>

#define BATCH   32768
#define DIM     2048
#define NHEADS  28
#define NCOLS   280
#define LOSS_SCALE (1.0f / (float)(BATCH * NHEADS))

typedef __attribute__((ext_vector_type(8))) short short8;
typedef __attribute__((ext_vector_type(4))) float f32x4;

__device__ __forceinline__ short f2bf(float f) {
    union { __hip_bfloat16 h; short s; } u; u.h = __float2bfloat16(f); return u.s;
}

// ---------------------------------------------------------------------------
// W pre-swizzle: W [280][2048] f32 -> Wswz bf16 in MFMA B-fragment order.
//   short index = (nt*64 + ktg)*512 + lane*8 + j
//   n = nt*16 + (lane&15), d = ktg*32 + (lane>>4)*8 + j   (ktg = k-granule of 32)
// ---------------------------------------------------------------------------
__global__ void mvh_swz(const float* __restrict__ W, short* __restrict__ Wswz) {
    int t = blockIdx.x * 256 + threadIdx.x;      // 73728 threads
    int lane = t & 63;
    int ks = (t >> 6) & 63;
    int nt = t >> 12;                            // 0..17
    int n = nt * 16 + (lane & 15);
    int d = ks * 32 + (lane >> 4) * 8;
    short8 v;
    #pragma unroll
    for (int j = 0; j < 8; j++) v[j] = 0;
    if (n < NCOLS) {
        const float* src = W + (size_t)n * DIM + d;
        #pragma unroll
        for (int j = 0; j < 8; j++) v[j] = f2bf(src[j]);
    }
    *(short8*)(Wswz + (size_t)t * 8) = v;
}

// ---------------------------------------------------------------------------
// GEMM: logits[b][n] = sum_d hidden[b][d]*W[n][d] + bias[n]
// grid 512 x 512 threads (8 waves). BM=64, BK=64, 32 K-tiles, 2 blocks/CU.
// Wave = 16 rows (wsub=wave>>1) x 144 cols (nhalf=wave&1), acc = 9 x f32x4.
// A: fp32 DMA (global_load_lds 16B) double-buffered LDS, XOR-32B swizzle
//    (source-side swizzle + swizzled ds_read).
// B: bf16 DMA from frag-ordered Wswz (L2-resident) into single LDS buffer.
// Sync discipline: __syncthreads x2 per tile (proven round-2 structure).
// ---------------------------------------------------------------------------
#define A_BYTES 16384
#define B_BYTES 36864

__global__ __launch_bounds__(512, 4)
void mvh_gemm(const float* __restrict__ hidden, const short* __restrict__ Wswz,
              const float* __restrict__ bias, float* __restrict__ logits) {
    __shared__ __align__(16) char lds[2 * A_BYTES + B_BYTES];   // 69632
    char* Ab0 = lds;
    char* Ab1 = lds + A_BYTES;
    char* Bb  = lds + 2 * A_BYTES;

    const int tid  = threadIdx.x;
    const int lane = tid & 63;
    const int wave = tid >> 6;          // 0..7
    const int nhalf = wave & 1;         // 144-col half
    const int wsub  = wave >> 1;        // 0..3: 16-row slice
    const int l15 = lane & 15, lhi = lane >> 4;
    const int rowbase = blockIdx.x * 64;

    f32x4 acc[9];
    #pragma unroll
    for (int n = 0; n < 9; n++) acc[n] = (f32x4)0.0f;

    // A staging: granule g (16B) -> LDS linear g*16 = row*256 + sub*16,
    // global source column bytes (sub*16) ^ ((row&7)<<5). 1024 granules, 2/thread.
#define STAGE_A(dstbase, kt) do { \
    _Pragma("unroll") \
    for (int i_ = 0; i_ < 2; i_++) { \
        int g_ = i_ * 512 + tid; \
        int row_ = g_ >> 4, sub_ = g_ & 15; \
        int gbyte_ = (sub_ * 16) ^ ((row_ & 7) << 5); \
        const float* gp_ = hidden + (size_t)(rowbase + row_) * DIM + (kt) * 64 + (gbyte_ >> 2); \
        char* lp_ = (dstbase) + g_ * 16; \
        __builtin_amdgcn_global_load_lds((const __attribute__((address_space(1))) void*)gp_, \
            (__attribute__((address_space(3))) void*)lp_, 16, 0, 0); \
    } \
} while (0)

    // B staging: granule g -> LDS g*16; f = g>>6 = nsub*2+ks, lane' = g&63.
    // src short-offset = (nsub*64 + kt*2 + ks)*512 + lane'*8. 2304 granules, 5 issues.
#define STAGE_B(kt) do { \
    _Pragma("unroll") \
    for (int i_ = 0; i_ < 5; i_++) { \
        int g_ = (i_ < 4) ? (i_ * 512 + tid) : (2048 + (tid & 255)); \
        int f_ = g_ >> 6; \
        const short* gp_ = Wswz + (size_t)((f_ >> 1) * 64 + (kt) * 2 + (f_ & 1)) * 512 + (g_ & 63) * 8; \
        char* lp_ = Bb + g_ * 16; \
        __builtin_amdgcn_global_load_lds((const __attribute__((address_space(1))) void*)gp_, \
            (__attribute__((address_space(3))) void*)lp_, 16, 0, 0); \
    } \
} while (0)

    // Per tile: 2 ks x (1 A-frag cvt + 9 MFMA)
#define COMPUTE(Abase) do { \
    _Pragma("unroll") \
    for (int ks_ = 0; ks_ < 2; ks_++) { \
        int arow_ = wsub * 16 + l15; \
        int kb_ = (ks_ * 128 + lhi * 32) ^ ((arow_ & 7) << 5); \
        const char* ap_ = (Abase) + arow_ * 256 + kb_; \
        f32x4 lo_ = *(const f32x4*)ap_; \
        f32x4 hi_ = *(const f32x4*)(ap_ + 16); \
        short8 af_; \
        _Pragma("unroll") \
        for (int j_ = 0; j_ < 4; j_++) { af_[j_] = f2bf(lo_[j_]); af_[4 + j_] = f2bf(hi_[j_]); } \
        _Pragma("unroll") \
        for (int n_ = 0; n_ < 9; n_++) { \
            short8 bf_ = *(const short8*)(Bb + ((nhalf * 9 + n_) * 2 + ks_) * 1024 + lane * 16); \
            acc[n_] = __builtin_amdgcn_mfma_f32_16x16x32_bf16(af_, bf_, acc[n_], 0, 0, 0); \
        } \
    } \
} while (0)

    // prologue
    STAGE_A(Ab0, 0);
    STAGE_B(0);

    #pragma unroll 1
    for (int t = 0; t < 32; t += 2) {
        __syncthreads();                 // A(t) in Ab0, B(t) in Bb ready
        STAGE_A(Ab1, t + 1);             // t <= 30 so t+1 <= 31 always valid
        COMPUTE(Ab0);
        __syncthreads();                 // B(t) reads done
        STAGE_B(t + 1);
        __syncthreads();                 // A(t+1) in Ab1, B(t+1) ready
        if (t + 2 < 32) STAGE_A(Ab0, t + 2);
        COMPUTE(Ab1);
        __syncthreads();                 // B(t+1) reads done
        if (t + 2 < 32) STAGE_B(t + 2);
    }

#undef STAGE_A
#undef STAGE_B
#undef COMPUTE

    // epilogue: bias + store. D frag: row = lhi*4 + r, col = l15.
    #pragma unroll
    for (int n = 0; n < 9; n++) {
        int c = nhalf * 144 + n * 16 + l15;
        if (c < NCOLS) {
            float bv = bias[c];
            int row0 = rowbase + wsub * 16 + lhi * 4;
            #pragma unroll
            for (int r = 0; r < 4; r++)
                logits[(size_t)(row0 + r) * NCOLS + c] = acc[n][r] + bv;
        }
    }
}

// ---------------------------------------------------------------------------
// Loss: one thread per (row, head). nll = logsumexp(10) - x[label].
// ---------------------------------------------------------------------------
__global__ __launch_bounds__(256)
void mvh_loss(const float* __restrict__ logits, const int* __restrict__ labels,
              float* __restrict__ loss_out) {
    int gid = blockIdx.x * 256 + threadIdx.x;    // 917504 = 3584*256 exactly
    const float* p = logits + (size_t)gid * 10;
    float x[10];
    #pragma unroll
    for (int j = 0; j < 10; j++) x[j] = p[j];
    float m = x[0];
    #pragma unroll
    for (int j = 1; j < 10; j++) m = fmaxf(m, x[j]);
    float s = 0.0f;
    #pragma unroll
    for (int j = 0; j < 10; j++) s += __expf(x[j] - m);
    int lab = labels[gid];
    float xl = x[0];
    #pragma unroll
    for (int j = 1; j < 10; j++) xl = (lab == j) ? x[j] : xl;
    float nll = m + __logf(s) - xl;

    #pragma unroll
    for (int off = 32; off > 0; off >>= 1)
        nll += __shfl_down(nll, off, 64);

    __shared__ float part[4];
    int lane = threadIdx.x & 63, wv = threadIdx.x >> 6;
    if (lane == 0) part[wv] = nll;
    __syncthreads();
    if (threadIdx.x == 0)
        atomicAdd(loss_out, (part[0] + part[1] + part[2] + part[3]) * LOSS_SCALE);
}

extern "C" void kernel_launch(void* const* d_in, const int* in_sizes, int n_in,
                              void* d_out, int out_size, void* d_ws, size_t ws_size,
                              hipStream_t stream) {
    const float* hidden = (const float*)d_in[0];
    const int* labels   = (const int*)d_in[1];
    const float* W      = (const float*)d_in[2];
    const float* bias   = (const float*)d_in[3];
    float* out = (float*)d_out;
    short* Wswz = (short*)d_ws;   // 589824 bf16 = 1.18 MB

    hipMemsetAsync(d_out, 0, sizeof(float), stream);           // zero loss accumulator
    mvh_swz<<<288, 256, 0, stream>>>(W, Wswz);
    mvh_gemm<<<512, 512, 0, stream>>>(hidden, Wswz, bias, out + 1);
    mvh_loss<<<3584, 256, 0, stream>>>(out + 1, labels, out);
}